// Round 12
// baseline (385.498 us; speedup 1.0000x reference)
//
#include <hip/hip_runtime.h>
#include <hip/hip_bf16.h>
#include <math.h>

// Problem constants: N=4096, D=512, H=8, DH=64, K_SEL=10, C=4
#define DEV __device__ __forceinline__

typedef __attribute__((ext_vector_type(4))) float  f32x4;
typedef __attribute__((ext_vector_type(8))) short  bf8_t;   // 8 x bf16 (4 VGPRs)
typedef unsigned int   u32;
typedef unsigned short u16;

DEV u16 f2bf(float f){
  u32 u = __builtin_bit_cast(u32, f);
  u32 r = (u + 0x7fffu + ((u >> 16) & 1u)) >> 16;   // RNE
  return (u16)r;
}
DEV float bf2f(u16 h){ u32 u = ((u32)h) << 16; return __builtin_bit_cast(float, u); }
// XOR-swizzle on 16B chunks with row&7 (bank-conflict fix for ds_read_b128)
DEV u32 swzB(u32 r, u32 b, u32 rowBytes){ return r*rowBytes + (b ^ ((r & 7u) << 4)); }

// async global->LDS, 16B per lane; lds base must be wave-uniform, global addr per-lane
DEV void gll16(const void* g, void* l){
  __builtin_amdgcn_global_load_lds(
      (const __attribute__((address_space(1))) unsigned int*)g,
      (__attribute__((address_space(3))) unsigned int*)l, 16, 0, 0);
}

// Per-branch strides (elements)
#define EL2M 2097152        // 4096*512
#define WBR  1310720        // 5 slots x 262144 u16 per branch (fc,q,k,v,wo)
#define PSTR 272            // P row stride in bytes (64+4 m-chunks -> conflict-free)
#define P1OFF 17408         // 64*272

// ---------------- weight split: per branch {fc,q,k,v,wo} transposed bf16 (hi only) --------------
__global__ void k_split_w(
    const float* __restrict__ A0, const float* __restrict__ A1,
    const float* __restrict__ A2, const float* __restrict__ A3,
    const float* __restrict__ A4,
    const float* __restrict__ B0, const float* __restrict__ B1,
    const float* __restrict__ B2, const float* __restrict__ B3,
    const float* __restrict__ B4, u16* __restrict__ ob)
{
  const int which = blockIdx.y, br = blockIdx.z;
  const float* w = br ? ((which==0)?B0:(which==1)?B1:(which==2)?B2:(which==3)?B3:B4)
                      : ((which==0)?A0:(which==1)?A1:(which==2)?A2:(which==3)?A3:A4);
  int i = blockIdx.x*256 + threadIdx.x;       // over 512*512
  int k = i >> 9, c = i & 511;
  u16* base = ob + (size_t)br*WBR;
  base[which*262144 + c*512 + k] = f2bf(w[i]);
}

// ---------------- LayerNorm -> bf16 ----------------
__global__ __launch_bounds__(256) void k_ln(
    const float* __restrict__ xg, const float* __restrict__ g0, const float* __restrict__ b0,
    const float* __restrict__ g1, const float* __restrict__ b1, u16* __restrict__ shiB)
{
  const int br = blockIdx.y;
  const float* x = xg + (size_t)br*EL2M;
  const float* g = br ? g1 : g0;
  const float* b = br ? b1 : b0;
  u16* out = shiB + (size_t)br*EL2M;
  const int w = threadIdx.x >> 6, lane = threadIdx.x & 63;
  const int row = blockIdx.x*4 + w;
  const float* xr = x + row*512;
  float v[8];
  f32x4 a  = *(const f32x4*)(xr + lane*8);
  f32x4 a2 = *(const f32x4*)(xr + lane*8 + 4);
  v[0]=a.x; v[1]=a.y; v[2]=a.z; v[3]=a.w; v[4]=a2.x; v[5]=a2.y; v[6]=a2.z; v[7]=a2.w;
  float s = v[0]+v[1]+v[2]+v[3]+v[4]+v[5]+v[6]+v[7];
  #pragma unroll
  for (int m=1;m<64;m<<=1) s += __shfl_xor(s, m);
  const float mean = s * (1.0f/512.0f);
  float q = 0.f;
  #pragma unroll
  for (int i=0;i<8;++i){ const float d = v[i]-mean; q += d*d; }
  #pragma unroll
  for (int m=1;m<64;m<<=1) q += __shfl_xor(q, m);
  const float rstd = 1.0f / sqrtf(q*(1.0f/512.0f) + 1e-5f);
  #pragma unroll
  for (int i=0;i<8;++i){
    const int c = lane*8 + i;
    out[row*512 + c] = f2bf((v[i]-mean)*rstd*g[c] + b[c]);
  }
}

// ---------------- fc GEMM: A = fp32 x -> bf16 in staging, 1-term, GELU epilogue, z=branch --------
__global__ __launch_bounds__(256) void k_gemm_fc(
    const float* __restrict__ X0, const float* __restrict__ X1,
    const u16* __restrict__ wb,
    const float* __restrict__ b0, const float* __restrict__ b1,
    float* __restrict__ xgB)
{
  __shared__ __align__(16) char ls[16384];   // A@0, B@8192
  const int br = blockIdx.z;
  const float* X = br ? X1 : X0;
  const float* bias = br ? b1 : b0;
  const u16* Bthi = wb + (size_t)br*WBR;     // slot 0
  float* outF = xgB + (size_t)br*EL2M;
  const int t = threadIdx.x;
  const int w = t >> 6, lane = t & 63;
  const int n0 = blockIdx.x * 64;
  const int c0 = blockIdx.y * 64;
  const int wr = w >> 1, wc = w & 1;
  const int lr = lane & 15, lg = lane >> 4;

  auto stageB = [&](const u16* __restrict__ src, char* lbase, int row0, int kb){
    #pragma unroll
    for (int j=0;j<2;++j){
      const int ci = w*128 + j*64 + lane;
      const int r  = ci >> 3, cl = ci & 7;
      const int cs = cl ^ (r & 7);
      gll16(src + (size_t)(row0 + r)*512 + kb + cs*8, lbase + w*2048 + j*1024);
    }
  };

  f32x4 acc[2][2];
  #pragma unroll
  for (int i=0;i<2;++i)
    #pragma unroll
    for (int j=0;j<2;++j) acc[i][j] = f32x4{0.f,0.f,0.f,0.f};

  for (int bk = 0; bk < 8; ++bk) {
    const int kb = bk * 64;
    __syncthreads();
    stageB(Bthi, ls + 8192, c0, kb);
    #pragma unroll 4
    for (int i = t; i < 1024; i += 256) {
      const int r = i >> 4, c = i & 15;
      const f32x4 xv = *(const f32x4*)(X + (n0 + r)*512 + kb + c*4);
      u32 h01, h23;
      asm("v_cvt_pk_bf16_f32 %0, %1, %2" : "=v"(h01) : "v"(xv.x), "v"(xv.y));
      asm("v_cvt_pk_bf16_f32 %0, %1, %2" : "=v"(h23) : "v"(xv.z), "v"(xv.w));
      *(uint2*)(ls + swzB(r, c*8, 128)) = uint2{h01, h23};
    }
    __syncthreads();
    #pragma unroll
    for (int ks = 0; ks < 2; ++ks) {
      const u32 co = ks*64 + lg*16;
      bf8_t ah[2], bh[2];
      #pragma unroll
      for (int i=0;i<2;++i) {
        ah[i] = *(const bf8_t*)(ls +        swzB(wr*32 + i*16 + lr, co, 128));
        bh[i] = *(const bf8_t*)(ls + 8192 + swzB(wc*32 + i*16 + lr, co, 128));
      }
      #pragma unroll
      for (int i=0;i<2;++i)
        #pragma unroll
        for (int j=0;j<2;++j)
          acc[i][j] = __builtin_amdgcn_mfma_f32_16x16x32_bf16(ah[i], bh[j], acc[i][j], 0,0,0);
    }
  }
  #pragma unroll
  for (int i=0;i<2;++i)
    #pragma unroll
    for (int j=0;j<2;++j) {
      const int col = c0 + wc*32 + j*16 + lr;
      #pragma unroll
      for (int r=0;r<4;++r) {
        const int row = n0 + wr*32 + i*16 + lg*4 + r;
        float v = acc[i][j][r] + bias[col];
        outF[row*512 + col] = 0.5f * v * (1.0f + erff(v * 0.70710678118654752f));
      }
    }
}

// ---------------- Q/K/V GEMM: 1-term, z = br*3 + {0:Q, 1:K, 2:V^T}, async staging ----------------
__global__ __launch_bounds__(256) void k_gemm_qkv(
    const u16* __restrict__ shiB, const u16* __restrict__ wb,
    u16* __restrict__ qhB, u16* __restrict__ khB, u16* __restrict__ vTB)
{
  __shared__ __align__(16) char ls[16384];   // A@0, B@8192
  const int z = blockIdx.z;
  const int br = z / 3, which = z % 3;
  const u16* Ahi  = shiB + (size_t)br*EL2M;
  const u16* Bthi = wb + (size_t)br*WBR + (size_t)(1+which)*262144;
  const int t = threadIdx.x;
  const int w = t >> 6, lane = t & 63;
  const int n0 = blockIdx.x * 64;
  const int c0 = blockIdx.y * 64;
  const int wr = w >> 1, wc = w & 1;
  const int lr = lane & 15, lg = lane >> 4;

  auto stage = [&](const u16* __restrict__ src, char* lbase, int row0, int kb){
    #pragma unroll
    for (int j=0;j<2;++j){
      const int ci = w*128 + j*64 + lane;
      const int r  = ci >> 3, cl = ci & 7;
      const int cs = cl ^ (r & 7);
      gll16(src + (size_t)(row0 + r)*512 + kb + cs*8, lbase + w*2048 + j*1024);
    }
  };

  f32x4 acc[2][2];
  #pragma unroll
  for (int i=0;i<2;++i)
    #pragma unroll
    for (int j=0;j<2;++j) acc[i][j] = f32x4{0.f,0.f,0.f,0.f};

  for (int bk = 0; bk < 8; ++bk) {
    const int kb = bk * 64;
    __syncthreads();
    stage(Ahi,  ls,        n0, kb);
    stage(Bthi, ls + 8192, c0, kb);
    __syncthreads();
    #pragma unroll
    for (int ks = 0; ks < 2; ++ks) {
      const u32 co = ks*64 + lg*16;
      bf8_t ah[2], bh[2];
      #pragma unroll
      for (int i=0;i<2;++i) {
        ah[i] = *(const bf8_t*)(ls +        swzB(wr*32 + i*16 + lr, co, 128));
        bh[i] = *(const bf8_t*)(ls + 8192 + swzB(wc*32 + i*16 + lr, co, 128));
      }
      #pragma unroll
      for (int i=0;i<2;++i)
        #pragma unroll
        for (int j=0;j<2;++j)
          acc[i][j] = __builtin_amdgcn_mfma_f32_16x16x32_bf16(ah[i], bh[j], acc[i][j], 0,0,0);
    }
  }
  u16* outQ = qhB + (size_t)br*EL2M;
  u16* outK = khB + (size_t)br*EL2M;
  u16* outV = vTB + (size_t)br*EL2M;
  #pragma unroll
  for (int i=0;i<2;++i)
    #pragma unroll
    for (int j=0;j<2;++j) {
      const int col = c0 + wc*32 + j*16 + lr;
      #pragma unroll
      for (int r=0;r<4;++r) {
        const int row = n0 + wr*32 + i*16 + lg*4 + r;
        const u16 hv = f2bf(acc[i][j][r]);
        if (which == 2)      outV[(size_t)col*4096 + row] = hv;   // V^T [d][n]
        else if (which == 1) outK[row*512 + col] = hv;
        else                 outQ[row*512 + col] = hv;
      }
    }
}

// ---------------- fused attention v5: deferred normalization ----------------
// Pass A (heavy): QK^T -> e=exp2(s*cexp) -> rowsums, P=bf16(e) (padded stride), PV unnormalized.
// Reduce l -> rinv. Pass B (light, barrier-free): QK^T -> colsums with e*u -> Apart.
// O = oacc * rinv at write. grid 1024 = 2 branches x 8 heads x 64 n-blocks.
__global__ __launch_bounds__(256) void k_attn(
    const u16* __restrict__ qhiB, const u16* __restrict__ khiB,
    const u16* __restrict__ vtB,  u16* __restrict__ ovB, float* __restrict__ ApartB)
{
  __shared__ __align__(16) char ls[34816];   // P0@0, P1@17408 (stride 272); red/rinv alias P0 after pass A
  const int t = threadIdx.x, w = t >> 6, lane = t & 63;
  const int lr = lane & 15, lg = lane >> 4;
  const int bid = blockIdx.x;
  const int h = bid & 7, br = (bid >> 3) & 1, nb = bid >> 4;   // head per XCD
  const int n0 = nb * 64, qc0 = h * 64;
  const u16* qhi = qhiB + (size_t)br*EL2M;
  const u16* khi = khiB + (size_t)br*EL2M;
  const u16* vt  = vtB  + (size_t)br*EL2M;
  u16* ov        = ovB  + (size_t)br*EL2M;
  float* Apart   = ApartB + (size_t)br*EL2M;
  const float cexp = 0.18033688011112042f;   // log2(e)/8

  bf8_t qf[4][2];
  #pragma unroll
  for (int b=0;b<4;++b)
    #pragma unroll
    for (int ks=0;ks<2;++ks)
      qf[b][ks] = *(const bf8_t*)(qhi + (n0 + b*16 + lr)*512 + qc0 + ks*32 + lg*8);

  const u16* kbase = khi + (size_t)(w*32 + lr)*512 + qc0 + lg*8;
  const u16* vbase = vt + (size_t)(qc0 + w*16 + lr)*4096 + lg*8;

  auto loadK = [&](int mt, bf8_t (&kk)[2][2]){
    const u16* kb = kbase + (size_t)(mt*128)*512;
    #pragma unroll
    for (int ks=0;ks<2;++ks){
      kk[0][ks] = *(const bf8_t*)(kb + ks*32);
      kk[1][ks] = *(const bf8_t*)(kb + 16*512 + ks*32);
    }
  };
  auto loadV = [&](int mt, bf8_t (&vv)[4]){
    #pragma unroll
    for (int k2=0;k2<4;++k2) vv[k2] = *(const bf8_t*)(vbase + mt*128 + k2*32);
  };

  // ---- pass A: raw-e P + PV + rowsums ----
  f32x4 oacc[4];
  #pragma unroll
  for (int i=0;i<4;++i) oacc[i] = f32x4{0.f,0.f,0.f,0.f};
  float rs[4] = {0.f,0.f,0.f,0.f};
  {
    bf8_t kA[2][2], kB[2][2], vA[4], vB[4];
    loadK(0, kA); loadV(0, vA);
    loadK(1, kB); loadV(1, vB);
    auto stepA = [&](int mt, bf8_t (&kk)[2][2], bf8_t (&vv)[4], u32 pb){
      f32x4 sacc[2][4];
      #pragma unroll
      for (int a=0;a<2;++a)
        #pragma unroll
        for (int b=0;b<4;++b) sacc[a][b] = f32x4{0.f,0.f,0.f,0.f};
      #pragma unroll
      for (int ks=0;ks<2;++ks)
        #pragma unroll
        for (int b=0;b<4;++b){
          sacc[0][b] = __builtin_amdgcn_mfma_f32_16x16x32_bf16(kk[0][ks], qf[b][ks], sacc[0][b], 0,0,0);
          sacc[1][b] = __builtin_amdgcn_mfma_f32_16x16x32_bf16(kk[1][ks], qf[b][ks], sacc[1][b], 0,0,0);
        }
      if (mt+2 < 32) loadK(mt+2, kk);
      #pragma unroll
      for (int a=0;a<2;++a){
        const u32 mb = w*64 + a*32 + lg*8;
        #pragma unroll
        for (int b=0;b<4;++b){
          const float e0 = __builtin_amdgcn_exp2f(sacc[a][b][0]*cexp);
          const float e1 = __builtin_amdgcn_exp2f(sacc[a][b][1]*cexp);
          const float e2 = __builtin_amdgcn_exp2f(sacc[a][b][2]*cexp);
          const float e3 = __builtin_amdgcn_exp2f(sacc[a][b][3]*cexp);
          rs[b] += (e0+e1)+(e2+e3);
          u32 u01, u23;
          asm("v_cvt_pk_bf16_f32 %0, %1, %2" : "=v"(u01) : "v"(e0), "v"(e1));
          asm("v_cvt_pk_bf16_f32 %0, %1, %2" : "=v"(u23) : "v"(e2), "v"(e3));
          *(uint2*)(ls + pb + (u32)(b*16 + lr)*PSTR + mb) = uint2{u01, u23};
        }
      }
      __syncthreads();                       // P[pb] fully written (other buffer untouched)
      #pragma unroll
      for (int ks2 = 0; ks2 < 4; ++ks2) {
        const u32 co = ks2*64 + lg*16;
        #pragma unroll
        for (int i=0;i<4;++i){
          const bf8_t ap = *(const bf8_t*)(ls + pb + (u32)(i*16 + lr)*PSTR + co);
          oacc[i] = __builtin_amdgcn_mfma_f32_16x16x32_bf16(ap, vv[ks2], oacc[i], 0,0,0);
        }
      }
      if (mt+2 < 32) loadV(mt+2, vv);
    };
    for (int mt = 0; mt < 32; mt += 2){
      stepA(mt,   kA, vA, 0);
      stepA(mt+1, kB, vB, P1OFF);
    }
  }

  // ---- reduce rowsums -> rinv (aliases P0, dead now) ----
  #pragma unroll
  for (int b=0;b<4;++b){ rs[b] += __shfl_xor(rs[b],16); rs[b] += __shfl_xor(rs[b],32); }
  __syncthreads();
  {
    float* red = (float*)ls;                 // [4 waves][64 n]
    if (lg == 0){
      #pragma unroll
      for (int b=0;b<4;++b) red[w*64 + b*16 + lr] = rs[b];
    }
    __syncthreads();
    float* rinv = (float*)(ls + 1024);
    if (t < 64) rinv[t] = 1.0f / (red[t] + red[64+t] + red[128+t] + red[192+t]);
    __syncthreads();
  }
  float lrv[4];
  #pragma unroll
  for (int b=0;b<4;++b) lrv[b] = log2f(((const float*)(ls + 1024))[b*16 + lr]);

  // ---- pass B: colsums -> Apart (barrier-free streaming) ----
  {
    bf8_t kA[2][2], kB[2][2];
    loadK(0, kA); loadK(1, kB);
    auto stepB = [&](int mt, bf8_t (&kk)[2][2]){
      f32x4 sacc[2][4];
      #pragma unroll
      for (int a=0;a<2;++a)
        #pragma unroll
        for (int b=0;b<4;++b) sacc[a][b] = f32x4{0.f,0.f,0.f,0.f};
      #pragma unroll
      for (int ks=0;ks<2;++ks)
        #pragma unroll
        for (int b=0;b<4;++b){
          sacc[0][b] = __builtin_amdgcn_mfma_f32_16x16x32_bf16(kk[0][ks], qf[b][ks], sacc[0][b], 0,0,0);
          sacc[1][b] = __builtin_amdgcn_mfma_f32_16x16x32_bf16(kk[1][ks], qf[b][ks], sacc[1][b], 0,0,0);
        }
      if (mt+2 < 32) loadK(mt+2, kk);
      float cs[2][4];
      #pragma unroll
      for (int a=0;a<2;++a){ cs[a][0]=0.f; cs[a][1]=0.f; cs[a][2]=0.f; cs[a][3]=0.f; }
      #pragma unroll
      for (int a=0;a<2;++a)
        #pragma unroll
        for (int b=0;b<4;++b){
          cs[a][0] += __builtin_amdgcn_exp2f(sacc[a][b][0]*cexp + lrv[b]);
          cs[a][1] += __builtin_amdgcn_exp2f(sacc[a][b][1]*cexp + lrv[b]);
          cs[a][2] += __builtin_amdgcn_exp2f(sacc[a][b][2]*cexp + lrv[b]);
          cs[a][3] += __builtin_amdgcn_exp2f(sacc[a][b][3]*cexp + lrv[b]);
        }
      #pragma unroll
      for (int a=0;a<2;++a)
        #pragma unroll
        for (int r=0;r<4;++r){
          float v = cs[a][r];
          v += __shfl_xor(v,1); v += __shfl_xor(v,2);
          v += __shfl_xor(v,4); v += __shfl_xor(v,8);
          cs[a][r] = v;
        }
      if (lr == 0){
        const int base = (h*64 + nb)*4096 + mt*128 + w*32;
        #pragma unroll
        for (int a=0;a<2;++a)
          #pragma unroll
          for (int r=0;r<4;++r)
            Apart[base + a*16 + lg*4 + r] = cs[a][r];
      }
    };
    for (int mt = 0; mt < 32; mt += 2){
      stepB(mt,   kA);
      stepB(mt+1, kB);
    }
  }

  // ---- output: O = oacc * rinv[n] ----
  const float* rinv = (const float*)(ls + 1024);
  #pragma unroll
  for (int i=0;i<4;++i)
    #pragma unroll
    for (int r=0;r<4;++r){
      const int nl = i*16 + lg*4 + r;
      const int row = n0 + nl;
      const int col = qc0 + w*16 + lr;
      ov[row*512 + col] = f2bf(oacc[i][r] * rinv[nl]);
    }
}

// ---------------- A reduction: two-stage fp64 (deterministic fixed order), z/y = branch ----------
__global__ void k_reduceA1(const float* __restrict__ ApartB, double* __restrict__ A64p){
  const int br = blockIdx.z;
  const float* Apart = ApartB + (size_t)br*EL2M;
  const int m = blockIdx.x*256 + threadIdx.x;
  const int kb = blockIdx.y;                 // 8 chunks of 64 rows
  double s = 0.0;
  for (int b = kb*64; b < kb*64 + 64; ++b) s += (double)Apart[b*4096 + m];
  A64p[br*32768 + kb*4096 + m] = s;
}
__global__ void k_reduceA2(const double* __restrict__ A64p, double* __restrict__ A64){
  const int br = blockIdx.y;
  const int m = blockIdx.x*256 + threadIdx.x;
  double s = 0.0;
  #pragma unroll
  for (int kb=0;kb<8;++kb) s += A64p[br*32768 + kb*4096 + m];
  A64[br*4096 + m] = s;
}

// ---------------- exact stable-argsort top/bottom-K (wave-reduce version) ----------------
__global__ __launch_bounds__(256) void k_select(const double* __restrict__ A64B, int* __restrict__ idxB){
  __shared__ double Aw[4096];
  __shared__ double wv_[4];
  __shared__ int    wi_[4];
  const double* A64 = A64B + (size_t)blockIdx.x*4096;
  int* idx = idxB + blockIdx.x*32;
  const int t = threadIdx.x, w = t >> 6, lane = t & 63;
  for (int i=t;i<4096;i+=256) Aw[i] = A64[i];
  __syncthreads();
  for (int k=0;k<10;++k){                         // top-K: max, tie -> smaller index
    double best = -1e300; int bidx = 1<<30;
    for (int i=t;i<4096;i+=256){
      const double v = Aw[i];
      if (v > best){ best = v; bidx = i; }
    }
    #pragma unroll
    for (int m=1;m<64;m<<=1){
      const double ovv = __shfl_xor(best, m);
      const int    oii = __shfl_xor(bidx, m);
      if (ovv > best || (ovv == best && oii < bidx)){ best = ovv; bidx = oii; }
    }
    if (lane == 0){ wv_[w] = best; wi_[w] = bidx; }
    __syncthreads();
    if (t == 0){
      double bb = wv_[0]; int bi2 = wi_[0];
      #pragma unroll
      for (int q=1;q<4;++q)
        if (wv_[q] > bb || (wv_[q] == bb && wi_[q] < bi2)){ bb = wv_[q]; bi2 = wi_[q]; }
      idx[k] = bi2; Aw[bi2] = -1e300;
    }
    __syncthreads();
  }
  for (int i=t;i<4096;i+=256) Aw[i] = A64[i];
  __syncthreads();
  for (int k=0;k<10;++k){                         // bottom-K from the end: min, tie -> larger index
    double best = 1e300; int bidx = -1;
    for (int i=t;i<4096;i+=256){
      const double v = Aw[i];
      if (v < best || (v == best && i > bidx)){ best = v; bidx = i; }
    }
    #pragma unroll
    for (int m=1;m<64;m<<=1){
      const double ovv = __shfl_xor(best, m);
      const int    oii = __shfl_xor(bidx, m);
      if (ovv < best || (ovv == best && oii > bidx)){ best = ovv; bidx = oii; }
    }
    if (lane == 0){ wv_[w] = best; wi_[w] = bidx; }
    __syncthreads();
    if (t == 0){
      double bb = wv_[0]; int bi2 = wi_[0];
      #pragma unroll
      for (int q=1;q<4;++q)
        if (wv_[q] < bb || (wv_[q] == bb && wi_[q] > bi2)){ bb = wv_[q]; bi2 = wi_[q]; }
      idx[19-k] = bi2; Aw[bi2] = 1e300;
    }
    __syncthreads();
  }
}

// ---------------- residual GEMM (Wo): 1-term, residual epilogue, z=branch, async staging ----------
__global__ __launch_bounds__(256) void k_gemm_wo(
    const u16* __restrict__ ovB, const u16* __restrict__ wb,
    const float* __restrict__ xgB, float* __restrict__ AXB)
{
  __shared__ __align__(16) char ls[16384];   // A@0, B@8192
  const int br = blockIdx.z;
  const u16* Ahi  = ovB + (size_t)br*EL2M;
  const u16* Bthi = wb + (size_t)br*WBR + 4*262144;
  const float* resid = xgB + (size_t)br*EL2M;
  float* outF = AXB + (size_t)br*EL2M;
  const int t = threadIdx.x;
  const int w = t >> 6, lane = t & 63;
  const int n0 = blockIdx.x * 64;
  const int c0 = blockIdx.y * 64;
  const int wr = w >> 1, wc = w & 1;
  const int lr = lane & 15, lg = lane >> 4;

  auto stage = [&](const u16* __restrict__ src, char* lbase, int row0, int kb){
    #pragma unroll
    for (int j=0;j<2;++j){
      const int ci = w*128 + j*64 + lane;
      const int r  = ci >> 3, cl = ci & 7;
      const int cs = cl ^ (r & 7);
      gll16(src + (size_t)(row0 + r)*512 + kb + cs*8, lbase + w*2048 + j*1024);
    }
  };

  f32x4 acc[2][2];
  #pragma unroll
  for (int i=0;i<2;++i)
    #pragma unroll
    for (int j=0;j<2;++j) acc[i][j] = f32x4{0.f,0.f,0.f,0.f};

  for (int bk = 0; bk < 8; ++bk) {
    const int kb = bk * 64;
    __syncthreads();
    stage(Ahi,  ls,        n0, kb);
    stage(Bthi, ls + 8192, c0, kb);
    __syncthreads();
    #pragma unroll
    for (int ks = 0; ks < 2; ++ks) {
      const u32 co = ks*64 + lg*16;
      bf8_t ah[2], bh[2];
      #pragma unroll
      for (int i=0;i<2;++i) {
        ah[i] = *(const bf8_t*)(ls +        swzB(wr*32 + i*16 + lr, co, 128));
        bh[i] = *(const bf8_t*)(ls + 8192 + swzB(wc*32 + i*16 + lr, co, 128));
      }
      #pragma unroll
      for (int i=0;i<2;++i)
        #pragma unroll
        for (int j=0;j<2;++j)
          acc[i][j] = __builtin_amdgcn_mfma_f32_16x16x32_bf16(ah[i], bh[j], acc[i][j], 0,0,0);
    }
  }
  #pragma unroll
  for (int i=0;i<2;++i)
    #pragma unroll
    for (int j=0;j<2;++j) {
      const int col = c0 + wc*32 + j*16 + lr;
      #pragma unroll
      for (int r=0;r<4;++r) {
        const int row = n0 + wr*32 + i*16 + lg*4 + r;
        outF[row*512 + col] = acc[i][j][r] + resid[row*512 + col];
      }
    }
}

// ---------------- feats = LN(x_res): mean over rows (partials), and selected rows ----------------
__global__ __launch_bounds__(256) void k_slide_part(const float* __restrict__ AXB,
                                                    float* __restrict__ spartB){
  __shared__ float acc[4][512];
  const int br = blockIdx.y;
  const float* xres = AXB + (size_t)br*EL2M;
  float* spart = spartB + (size_t)br*32768;
  const int t = threadIdx.x, w = t >> 6, lane = t & 63;
  float la[8];
  #pragma unroll
  for (int i=0;i<8;++i) la[i]=0.f;
  for (int rr = 0; rr < 16; ++rr) {
    const int row = blockIdx.x*64 + w*16 + rr;
    const float* xr = xres + row*512;
    float v[8];
    f32x4 a  = *(const f32x4*)(xr + lane*8);
    f32x4 a2 = *(const f32x4*)(xr + lane*8 + 4);
    v[0]=a.x; v[1]=a.y; v[2]=a.z; v[3]=a.w; v[4]=a2.x; v[5]=a2.y; v[6]=a2.z; v[7]=a2.w;
    float s = v[0]+v[1]+v[2]+v[3]+v[4]+v[5]+v[6]+v[7];
    #pragma unroll
    for (int m=1;m<64;m<<=1) s += __shfl_xor(s, m);
    const float mean = s * (1.0f/512.0f);
    float q = 0.f;
    #pragma unroll
    for (int i=0;i<8;++i){ const float d = v[i]-mean; q += d*d; }
    #pragma unroll
    for (int m=1;m<64;m<<=1) q += __shfl_xor(q, m);
    const float rstd = 1.0f / sqrtf(q*(1.0f/512.0f) + 1e-5f);
    #pragma unroll
    for (int i=0;i<8;++i) la[i] += (v[i]-mean)*rstd;   // g,b applied at reduce (linear)
  }
  #pragma unroll
  for (int i=0;i<8;++i) acc[w][lane*8+i] = la[i];
  __syncthreads();
  for (int c = t; c < 512; c += 256)
    spart[blockIdx.x*512 + c] = acc[0][c]+acc[1][c]+acc[2][c]+acc[3][c];
}

__global__ void k_slide_reduce(const float* __restrict__ spartB, const float* __restrict__ g,
                               const float* __restrict__ b, float* __restrict__ tokB){
  const int br = blockIdx.y;
  const float* spart = spartB + (size_t)br*32768;
  const int c = blockIdx.x*256 + threadIdx.x;
  float s = 0.f;
  for (int bb=0;bb<64;++bb) s += spart[bb*512 + c];
  tokB[br*512 + c] = g[c]*(s*(1.0f/4096.0f)) + b[c];
}

__global__ void k_atte(const float* __restrict__ AXB, const int* __restrict__ idxB,
                       const float* __restrict__ g, const float* __restrict__ b,
                       float* __restrict__ atteB){
  const int br = blockIdx.y;
  const int i = blockIdx.x, lane = threadIdx.x;   // 64 threads = 1 wave
  const int row = idxB[br*32 + i];
  const float* xr = AXB + (size_t)br*EL2M + row*512;
  float v[8];
  f32x4 a  = *(const f32x4*)(xr + lane*8);
  f32x4 a2 = *(const f32x4*)(xr + lane*8 + 4);
  v[0]=a.x; v[1]=a.y; v[2]=a.z; v[3]=a.w; v[4]=a2.x; v[5]=a2.y; v[6]=a2.z; v[7]=a2.w;
  float s = v[0]+v[1]+v[2]+v[3]+v[4]+v[5]+v[6]+v[7];
  #pragma unroll
  for (int m=1;m<64;m<<=1) s += __shfl_xor(s, m);
  const float mean = s * (1.0f/512.0f);
  float q = 0.f;
  #pragma unroll
  for (int i2=0;i2<8;++i2){ const float d = v[i2]-mean; q += d*d; }
  #pragma unroll
  for (int m=1;m<64;m<<=1) q += __shfl_xor(q, m);
  const float rstd = 1.0f / sqrtf(q*(1.0f/512.0f) + 1e-5f);
  #pragma unroll
  for (int i2=0;i2<8;++i2){
    const int c = lane*8 + i2;
    atteB[br*10240 + i*512 + c] = (v[i2]-mean)*rstd*g[c] + b[c];
  }
}

// ---------------- head stage 1: concat GEMV split-K ----------------
__global__ __launch_bounds__(256) void k_fused_part(
    const float* __restrict__ tokB, const float* __restrict__ Wfc2,
    float* __restrict__ partF)
{
  __shared__ float part[8][32];
  const int t = threadIdx.x, jj = t & 31, rg = t >> 5;
  const int j = blockIdx.x*32 + jj;
  const int r0 = blockIdx.y*128;
  float s = 0.f;
  #pragma unroll 4
  for (int i = 0; i < 16; ++i){
    const int r = r0 + rg + i*8;
    s += tokB[r] * Wfc2[r*512 + j];   // tokB = [tokH(512) | tokI(512)] contiguous
  }
  part[rg][jj] = s;
  __syncthreads();
  if (t < 32){
    float acc = 0.f;
    #pragma unroll
    for (int g=0; g<8; ++g) acc += part[g][t];
    partF[blockIdx.y*512 + blockIdx.x*32 + t] = acc;
  }
}

__global__ void k_fused_fin(
    const float* __restrict__ tokB, const float* __restrict__ partF,
    const float* __restrict__ bfc2, float* __restrict__ fused)
{
  const int j = blockIdx.x*256 + threadIdx.x;   // 512
  float acc = bfc2[j];
  #pragma unroll
  for (int kb=0;kb<8;++kb) acc += partF[kb*512 + j];
  const float hv = tokB[j], iv = tokB[512 + j];
  fused[j]        = hv + iv;
  fused[512 + j]  = hv * iv;
  fused[1024 + j] = acc;
}

// ---------------- head stage 2: g1 GEMV split-K + GELU ----------------
__global__ __launch_bounds__(256) void k_g1_part(
    const float* __restrict__ fused, const float* __restrict__ Wc1,
    float* __restrict__ partG)
{
  __shared__ float part[8][32];
  const int t = threadIdx.x, jj = t & 31, rg = t >> 5;
  const int j = blockIdx.x*32 + jj;
  const int r0 = blockIdx.y*128;
  float s = 0.f;
  #pragma unroll 4
  for (int i = 0; i < 16; ++i){
    const int r = r0 + rg + i*8;
    s += fused[r] * Wc1[r*512 + j];
  }
  part[rg][jj] = s;
  __syncthreads();
  if (t < 32){
    float acc = 0.f;
    #pragma unroll
    for (int g=0; g<8; ++g) acc += part[g][t];
    partG[blockIdx.y*512 + blockIdx.x*32 + t] = acc;
  }
}

__global__ void k_g1_fin(const float* __restrict__ partG, const float* __restrict__ bc1,
                         float* __restrict__ g1)
{
  const int j = blockIdx.x*256 + threadIdx.x;   // 512
  float acc = bc1[j];
  #pragma unroll
  for (int kb=0;kb<12;++kb) acc += partG[kb*512 + j];
  g1[j] = 0.5f*acc*(1.0f + erff(acc*0.70710678118654752f));
}

// ---------------- head stage 3: Lm[20][20] cosine-sim matrix ----------------
__global__ __launch_bounds__(256) void k_lm(
    const float* __restrict__ atteB, const float* __restrict__ lscale, float* __restrict__ Lm)
{
  __shared__ float ra[512];
  __shared__ float nAs;
  const float* atteH = atteB;
  const float* atteI = atteB + 10240;
  const int a = blockIdx.x, t = threadIdx.x, w = t >> 6, l = t & 63;
  for (int i=t;i<512;i+=256) ra[i] = atteH[a*512+i];
  __syncthreads();
  if (w == 0){
    float s = 0.f;
    #pragma unroll
    for (int k=0;k<8;++k){ const float v = ra[l + k*64]; s += v*v; }
    #pragma unroll
    for (int m=1;m<64;m<<=1) s += __shfl_xor(s, m);
    if (l == 0) nAs = s;
  }
  __syncthreads();
  const float scale = expf(lscale[0]);
  const float nA = sqrtf(nAs);
  for (int bi = 0; bi < 5; ++bi){
    const int b = w + bi*4;
    float dot = 0.f, nb = 0.f;
    #pragma unroll
    for (int k=0;k<8;++k){
      const float vb = atteI[b*512 + l + k*64];
      dot += ra[l + k*64]*vb;
      nb  += vb*vb;
    }
    #pragma unroll
    for (int m=1;m<64;m<<=1){ dot += __shfl_xor(dot,m); nb += __shfl_xor(nb,m); }
    if (l == 0) Lm[a*20 + b] = scale * dot / (nA * sqrtf(nb));
  }
}

// ---------------- head stage 4: classifier logits + contrastive loss ----------------
__global__ __launch_bounds__(256) void k_loss(
    const float* __restrict__ tokB, const float* __restrict__ g1G, const float* __restrict__ LmG,
    const float* __restrict__ WheC, const float* __restrict__ bheC,
    const float* __restrict__ WihcC, const float* __restrict__ bihcC,
    const float* __restrict__ Wc2, const float* __restrict__ bc2,
    float* __restrict__ out)
{
  __shared__ float sH[512], sI[512], g1[512];
  __shared__ float Lm[20][20];
  __shared__ double terms[512];
  const int t = threadIdx.x, w = t >> 6, l = t & 63;
  for (int i=t;i<512;i+=256){ sH[i]=tokB[i]; sI[i]=tokB[512+i]; g1[i]=g1G[i]; }
  for (int i=t;i<400;i+=256) ((float*)Lm)[i] = LmG[i];
  __syncthreads();
  if (w < 3){
    const float* x  = (w==0)? sH   : (w==1)? sI    : g1;
    const float* W  = (w==0)? WheC : (w==1)? WihcC : Wc2;
    const float* bb = (w==0)? bheC : (w==1)? bihcC : bc2;
    const int c = l & 3, rg = l >> 2;
    float s = 0.f;
    for (int r = rg; r < 512; r += 16) s += x[r]*W[r*4+c];
    #pragma unroll
    for (int m=4;m<64;m<<=1) s += __shfl_xor(s, m);
    if (rg == 0) out[w*4 + c] = s + bb[c];
  }
  for (int e=t;e<512;e+=256){
    double res = 0.0;
    if (e < 400){
      const int r = e % 10, part = (e/10) % 2, i2 = (e/20) % 10, half = e/200;
      const int a = part ? (10 + r) : r;
      const int c0 = part ? (10 + i2) : i2;
      const int qb = part ? 0 : 10;
      auto Mget = [&](int aa, int bb)->double{
        return (double)(half ? Lm[bb][aa] : Lm[aa][bb]);
      };
      const double v0 = Mget(a, c0);
      double mx = v0;
      #pragma unroll
      for (int q=0;q<10;++q){ const double v = Mget(a, qb+q); if (v > mx) mx = v; }
      double se = exp(v0 - mx);
      #pragma unroll
      for (int q=0;q<10;++q) se += exp(Mget(a, qb+q) - mx);
      res = (log(se) + mx) - v0;
    }
    terms[e] = res;
  }
  __syncthreads();
  for (int s2=256;s2>0;s2>>=1){
    if (t < s2) terms[t] += terms[t+s2];
    __syncthreads();
  }
  if (t == 0) {
    const float cl = (float)(terms[0] / 400.0);
    out[12]=cl; out[13]=cl; out[14]=cl; out[15]=cl;
  }
}

// ---------------- launcher ----------------
extern "C" void kernel_launch(void* const* d_in, const int* in_sizes, int n_in,
                              void* d_out, int out_size, void* d_ws, size_t ws_size,
                              hipStream_t stream)
{
  (void)in_sizes; (void)n_in; (void)out_size; (void)ws_size;
  auto F = [&](int i){ return (const float*)d_in[i]; };
  char* ws = (char*)d_ws;
  size_t off = 0;
  auto alloc = [&](size_t sz)->void*{ void* p = ws + off; off += (sz + 255) & ~((size_t)255); return p; };

  float* xg   = (float*)alloc((size_t)2*EL2M*4);     // gelu(fc) output, 2 branches
  float* AX   = (float*)alloc((size_t)2*EL2M*4);     // Apart, later x_res, 2 branches
  u16*   shi  = (u16*)alloc((size_t)2*EL2M*2);       // LN(h) bf16
  u16*   qh   = (u16*)alloc((size_t)2*EL2M*2);
  u16*   kh   = (u16*)alloc((size_t)2*EL2M*2);
  u16*   vT   = (u16*)alloc((size_t)2*EL2M*2);       // V^T [d][n]
  u16*   ov   = (u16*)alloc((size_t)2*EL2M*2);       // attn out (pre-Wo)
  u16*   wb   = (u16*)alloc((size_t)2*WBR*2);        // weights: 5 slots x 2 branches
  double* A64p= (double*)alloc((size_t)2*32768*8);
  double* A64 = (double*)alloc((size_t)2*4096*8);
  int*   idxB = (int*)alloc(2*32*4);
  float* spart= (float*)alloc((size_t)2*32768*4);
  float* tokB = (float*)alloc(2*512*4);
  float* attB = (float*)alloc((size_t)2*10240*4);
  float* fusedW = (float*)alloc(1536*4);
  float* g1W    = (float*)alloc(512*4);
  float* LmW    = (float*)alloc(400*4);
  float* partF  = (float*)alloc((size_t)8*512*4);
  float* partG  = (float*)alloc((size_t)12*512*4);

  k_split_w<<<dim3(1024,5,2),256,0,stream>>>(
      F(2),F(8),F(9),F(10),F(11),      // HE:  Wfc Wq Wk Wv Wo
      F(4),F(14),F(15),F(16),F(17),    // IHC: Wfc Wq Wk Wv Wo
      wb);
  k_gemm_fc<<<dim3(64,8,2),256,0,stream>>>(F(0), F(1), wb, F(3), F(5), xg);
  k_ln<<<dim3(1024,2),256,0,stream>>>(xg, F(6), F(7), F(12), F(13), shi);
  k_gemm_qkv<<<dim3(64,8,6),256,0,stream>>>(shi, wb, qh, kh, vT);
  k_attn<<<1024,256,0,stream>>>(qh, kh, vT, ov, AX);
  k_reduceA1<<<dim3(16,8,2),256,0,stream>>>(AX, A64p);
  k_reduceA2<<<dim3(16,2),256,0,stream>>>(A64p, A64);
  k_select<<<2,256,0,stream>>>(A64, idxB);
  k_gemm_wo<<<dim3(64,8,2),256,0,stream>>>(ov, wb, xg, AX);
  k_slide_part<<<dim3(64,2),256,0,stream>>>(AX, spart);
  k_slide_reduce<<<dim3(2,2),256,0,stream>>>(spart, F(18), F(19), tokB);
  k_atte<<<dim3(20,2),64,0,stream>>>(AX, idxB, F(18), F(19), attB);

  k_fused_part<<<dim3(16,8),256,0,stream>>>(tokB, F(24), partF);
  k_fused_fin<<<2,256,0,stream>>>(tokB, partF, F(25), fusedW);
  k_g1_part<<<dim3(16,12),256,0,stream>>>(fusedW, F(26), partG);
  k_g1_fin<<<2,256,0,stream>>>(partG, F(27), g1W);
  k_lm<<<20,256,0,stream>>>(attB, F(30), LmW);
  k_loss<<<1,256,0,stream>>>(tokB, g1W, LmW,
                             F(20), F(21), F(22), F(23), F(28), F(29),
                             (float*)d_out);
}

// Round 13
// 378.738 us; speedup vs baseline: 1.0178x; 1.0178x over previous
//
#include <hip/hip_runtime.h>
#include <hip/hip_bf16.h>
#include <math.h>

// Problem constants: N=4096, D=512, H=8, DH=64, K_SEL=10, C=4
#define DEV __device__ __forceinline__

typedef __attribute__((ext_vector_type(4))) float  f32x4;
typedef __attribute__((ext_vector_type(8))) short  bf8_t;   // 8 x bf16 (4 VGPRs)
typedef unsigned int   u32;
typedef unsigned short u16;

DEV u16 f2bf(float f){
  u32 u = __builtin_bit_cast(u32, f);
  u32 r = (u + 0x7fffu + ((u >> 16) & 1u)) >> 16;   // RNE
  return (u16)r;
}
DEV float bf2f(u16 h){ u32 u = ((u32)h) << 16; return __builtin_bit_cast(float, u); }
// XOR-swizzle on 16B chunks with row&7 (bank-conflict fix for ds_read_b128)
DEV u32 swzB(u32 r, u32 b, u32 rowBytes){ return r*rowBytes + (b ^ ((r & 7u) << 4)); }

// async global->LDS, 16B per lane; lds base must be wave-uniform, global addr per-lane
DEV void gll16(const void* g, void* l){
  __builtin_amdgcn_global_load_lds(
      (const __attribute__((address_space(1))) unsigned int*)g,
      (__attribute__((address_space(3))) unsigned int*)l, 16, 0, 0);
}

// Per-branch strides (elements)
#define EL2M 2097152        // 4096*512
#define WBR  1310720        // 5 slots x 262144 u16 per branch (fc,q,k,v,wo)

// ---------------- weight split: per branch {fc,q,k,v,wo} transposed bf16 (hi only) --------------
__global__ void k_split_w(
    const float* __restrict__ A0, const float* __restrict__ A1,
    const float* __restrict__ A2, const float* __restrict__ A3,
    const float* __restrict__ A4,
    const float* __restrict__ B0, const float* __restrict__ B1,
    const float* __restrict__ B2, const float* __restrict__ B3,
    const float* __restrict__ B4, u16* __restrict__ ob)
{
  const int which = blockIdx.y, br = blockIdx.z;
  const float* w = br ? ((which==0)?B0:(which==1)?B1:(which==2)?B2:(which==3)?B3:B4)
                      : ((which==0)?A0:(which==1)?A1:(which==2)?A2:(which==3)?A3:A4);
  int i = blockIdx.x*256 + threadIdx.x;       // over 512*512
  int k = i >> 9, c = i & 511;
  u16* base = ob + (size_t)br*WBR;
  base[which*262144 + c*512 + k] = f2bf(w[i]);
}

// ---------------- LayerNorm -> bf16 ----------------
__global__ __launch_bounds__(256) void k_ln(
    const float* __restrict__ xg, const float* __restrict__ g0, const float* __restrict__ b0,
    const float* __restrict__ g1, const float* __restrict__ b1, u16* __restrict__ shiB)
{
  const int br = blockIdx.y;
  const float* x = xg + (size_t)br*EL2M;
  const float* g = br ? g1 : g0;
  const float* b = br ? b1 : b0;
  u16* out = shiB + (size_t)br*EL2M;
  const int w = threadIdx.x >> 6, lane = threadIdx.x & 63;
  const int row = blockIdx.x*4 + w;
  const float* xr = x + row*512;
  float v[8];
  f32x4 a  = *(const f32x4*)(xr + lane*8);
  f32x4 a2 = *(const f32x4*)(xr + lane*8 + 4);
  v[0]=a.x; v[1]=a.y; v[2]=a.z; v[3]=a.w; v[4]=a2.x; v[5]=a2.y; v[6]=a2.z; v[7]=a2.w;
  float s = v[0]+v[1]+v[2]+v[3]+v[4]+v[5]+v[6]+v[7];
  #pragma unroll
  for (int m=1;m<64;m<<=1) s += __shfl_xor(s, m);
  const float mean = s * (1.0f/512.0f);
  float q = 0.f;
  #pragma unroll
  for (int i=0;i<8;++i){ const float d = v[i]-mean; q += d*d; }
  #pragma unroll
  for (int m=1;m<64;m<<=1) q += __shfl_xor(q, m);
  const float rstd = 1.0f / sqrtf(q*(1.0f/512.0f) + 1e-5f);
  #pragma unroll
  for (int i=0;i<8;++i){
    const int c = lane*8 + i;
    out[row*512 + c] = f2bf((v[i]-mean)*rstd*g[c] + b[c]);
  }
}

// ---------------- fc GEMM: A = fp32 x -> bf16 in staging, 1-term, GELU epilogue, z=branch --------
__global__ __launch_bounds__(256) void k_gemm_fc(
    const float* __restrict__ X0, const float* __restrict__ X1,
    const u16* __restrict__ wb,
    const float* __restrict__ b0, const float* __restrict__ b1,
    float* __restrict__ xgB)
{
  __shared__ __align__(16) char ls[16384];   // A@0, B@8192
  const int br = blockIdx.z;
  const float* X = br ? X1 : X0;
  const float* bias = br ? b1 : b0;
  const u16* Bthi = wb + (size_t)br*WBR;     // slot 0
  float* outF = xgB + (size_t)br*EL2M;
  const int t = threadIdx.x;
  const int w = t >> 6, lane = t & 63;
  const int n0 = blockIdx.x * 64;
  const int c0 = blockIdx.y * 64;
  const int wr = w >> 1, wc = w & 1;
  const int lr = lane & 15, lg = lane >> 4;

  auto stageB = [&](const u16* __restrict__ src, char* lbase, int row0, int kb){
    #pragma unroll
    for (int j=0;j<2;++j){
      const int ci = w*128 + j*64 + lane;
      const int r  = ci >> 3, cl = ci & 7;
      const int cs = cl ^ (r & 7);
      gll16(src + (size_t)(row0 + r)*512 + kb + cs*8, lbase + w*2048 + j*1024);
    }
  };

  f32x4 acc[2][2];
  #pragma unroll
  for (int i=0;i<2;++i)
    #pragma unroll
    for (int j=0;j<2;++j) acc[i][j] = f32x4{0.f,0.f,0.f,0.f};

  for (int bk = 0; bk < 8; ++bk) {
    const int kb = bk * 64;
    __syncthreads();
    stageB(Bthi, ls + 8192, c0, kb);
    #pragma unroll 4
    for (int i = t; i < 1024; i += 256) {
      const int r = i >> 4, c = i & 15;
      const f32x4 xv = *(const f32x4*)(X + (n0 + r)*512 + kb + c*4);
      u32 h01, h23;
      asm("v_cvt_pk_bf16_f32 %0, %1, %2" : "=v"(h01) : "v"(xv.x), "v"(xv.y));
      asm("v_cvt_pk_bf16_f32 %0, %1, %2" : "=v"(h23) : "v"(xv.z), "v"(xv.w));
      *(uint2*)(ls + swzB(r, c*8, 128)) = uint2{h01, h23};
    }
    __syncthreads();
    #pragma unroll
    for (int ks = 0; ks < 2; ++ks) {
      const u32 co = ks*64 + lg*16;
      bf8_t ah[2], bh[2];
      #pragma unroll
      for (int i=0;i<2;++i) {
        ah[i] = *(const bf8_t*)(ls +        swzB(wr*32 + i*16 + lr, co, 128));
        bh[i] = *(const bf8_t*)(ls + 8192 + swzB(wc*32 + i*16 + lr, co, 128));
      }
      #pragma unroll
      for (int i=0;i<2;++i)
        #pragma unroll
        for (int j=0;j<2;++j)
          acc[i][j] = __builtin_amdgcn_mfma_f32_16x16x32_bf16(ah[i], bh[j], acc[i][j], 0,0,0);
    }
  }
  #pragma unroll
  for (int i=0;i<2;++i)
    #pragma unroll
    for (int j=0;j<2;++j) {
      const int col = c0 + wc*32 + j*16 + lr;
      #pragma unroll
      for (int r=0;r<4;++r) {
        const int row = n0 + wr*32 + i*16 + lg*4 + r;
        float v = acc[i][j][r] + bias[col];
        outF[row*512 + col] = 0.5f * v * (1.0f + erff(v * 0.70710678118654752f));
      }
    }
}

// ---------------- merged Q/K/V GEMM: one A staging, 3 B tiles, 3 accumulators; z=branch ----------
__global__ __launch_bounds__(256) void k_gemm_qkv(
    const u16* __restrict__ shiB, const u16* __restrict__ wb,
    u16* __restrict__ qhB, u16* __restrict__ khB, u16* __restrict__ vTB)
{
  __shared__ __align__(16) char ls[32768];   // A@0, Bq@8192, Bk@16384, Bv@24576
  const int br = blockIdx.z;
  const u16* Ahi = shiB + (size_t)br*EL2M;
  const u16* Wq  = wb + (size_t)br*WBR + 1*262144;
  const u16* Wk  = wb + (size_t)br*WBR + 2*262144;
  const u16* Wv  = wb + (size_t)br*WBR + 3*262144;
  const int t = threadIdx.x;
  const int w = t >> 6, lane = t & 63;
  const int n0 = blockIdx.x * 64;
  const int c0 = blockIdx.y * 64;
  const int wr = w >> 1, wc = w & 1;
  const int lr = lane & 15, lg = lane >> 4;

  auto stage = [&](const u16* __restrict__ src, char* lbase, int row0, int kb){
    #pragma unroll
    for (int j=0;j<2;++j){
      const int ci = w*128 + j*64 + lane;
      const int r  = ci >> 3, cl = ci & 7;
      const int cs = cl ^ (r & 7);
      gll16(src + (size_t)(row0 + r)*512 + kb + cs*8, lbase + w*2048 + j*1024);
    }
  };

  f32x4 aq[2][2], ak[2][2], av[2][2];
  #pragma unroll
  for (int i=0;i<2;++i)
    #pragma unroll
    for (int j=0;j<2;++j){
      aq[i][j] = f32x4{0.f,0.f,0.f,0.f};
      ak[i][j] = f32x4{0.f,0.f,0.f,0.f};
      av[i][j] = f32x4{0.f,0.f,0.f,0.f};
    }

  for (int bk = 0; bk < 8; ++bk) {
    const int kb = bk * 64;
    __syncthreads();
    stage(Ahi, ls,         n0, kb);
    stage(Wq,  ls + 8192,  c0, kb);
    stage(Wk,  ls + 16384, c0, kb);
    stage(Wv,  ls + 24576, c0, kb);
    __syncthreads();
    #pragma unroll
    for (int ks = 0; ks < 2; ++ks) {
      const u32 co = ks*64 + lg*16;
      bf8_t ah[2], bq[2], bkf[2], bv[2];
      #pragma unroll
      for (int i=0;i<2;++i) {
        ah[i]  = *(const bf8_t*)(ls +         swzB(wr*32 + i*16 + lr, co, 128));
        bq[i]  = *(const bf8_t*)(ls + 8192  + swzB(wc*32 + i*16 + lr, co, 128));
        bkf[i] = *(const bf8_t*)(ls + 16384 + swzB(wc*32 + i*16 + lr, co, 128));
        bv[i]  = *(const bf8_t*)(ls + 24576 + swzB(wc*32 + i*16 + lr, co, 128));
      }
      #pragma unroll
      for (int i=0;i<2;++i)
        #pragma unroll
        for (int j=0;j<2;++j){
          aq[i][j] = __builtin_amdgcn_mfma_f32_16x16x32_bf16(ah[i], bq[j],  aq[i][j], 0,0,0);
          ak[i][j] = __builtin_amdgcn_mfma_f32_16x16x32_bf16(ah[i], bkf[j], ak[i][j], 0,0,0);
          av[i][j] = __builtin_amdgcn_mfma_f32_16x16x32_bf16(ah[i], bv[j],  av[i][j], 0,0,0);
        }
    }
  }
  u16* outQ = qhB + (size_t)br*EL2M;
  u16* outK = khB + (size_t)br*EL2M;
  u16* outV = vTB + (size_t)br*EL2M;
  #pragma unroll
  for (int i=0;i<2;++i)
    #pragma unroll
    for (int j=0;j<2;++j) {
      const int col = c0 + wc*32 + j*16 + lr;
      #pragma unroll
      for (int r=0;r<4;++r) {
        const int row = n0 + wr*32 + i*16 + lg*4 + r;
        outQ[row*512 + col] = f2bf(aq[i][j][r]);
        outK[row*512 + col] = f2bf(ak[i][j][r]);
        outV[(size_t)col*4096 + row] = f2bf(av[i][j][r]);   // V^T [d][n]
      }
    }
}

// ---------------- fused attention (round-11 best): 64 q-rows/block, software-pipelined ----------
// LDS exactly 32K: P0@0, P1@16384; red/rinv transiently alias P0 (consumed before P0 writes).
__global__ __launch_bounds__(256) void k_attn(
    const u16* __restrict__ qhiB, const u16* __restrict__ khiB,
    const u16* __restrict__ vtB,  u16* __restrict__ ovB, float* __restrict__ ApartB)
{
  __shared__ __align__(16) char ls[32768];
  const int t = threadIdx.x, w = t >> 6, lane = t & 63;
  const int lr = lane & 15, lg = lane >> 4;
  const int bid = blockIdx.x;
  const int h = bid & 7, br = (bid >> 3) & 1, nb = bid >> 4;   // head per XCD
  const int n0 = nb * 64, qc0 = h * 64;
  const u16* qhi = qhiB + (size_t)br*EL2M;
  const u16* khi = khiB + (size_t)br*EL2M;
  const u16* vt  = vtB  + (size_t)br*EL2M;
  u16* ov        = ovB  + (size_t)br*EL2M;
  float* Apart   = ApartB + (size_t)br*EL2M;
  const float cexp = 0.18033688011112042f;   // log2(e)/8

  bf8_t qf[4][2];
  #pragma unroll
  for (int b=0;b<4;++b)
    #pragma unroll
    for (int ks=0;ks<2;++ks)
      qf[b][ks] = *(const bf8_t*)(qhi + (n0 + b*16 + lr)*512 + qc0 + ks*32 + lg*8);

  const u16* kbase = khi + (size_t)(w*32 + lr)*512 + qc0 + lg*8;
  const u16* vbase = vt + (size_t)(qc0 + w*16 + lr)*4096 + lg*8;

  auto loadK = [&](int mt, bf8_t (&kk)[2][2]){
    const u16* kb = kbase + (size_t)(mt*128)*512;
    #pragma unroll
    for (int ks=0;ks<2;++ks){
      kk[0][ks] = *(const bf8_t*)(kb + ks*32);
      kk[1][ks] = *(const bf8_t*)(kb + 16*512 + ks*32);
    }
  };
  auto loadV = [&](int mt, bf8_t (&vv)[4]){
    #pragma unroll
    for (int k2=0;k2<4;++k2) vv[k2] = *(const bf8_t*)(vbase + mt*128 + k2*32);
  };

  // ---- pass 1: row sums l_n ----
  float rs[4] = {0.f,0.f,0.f,0.f};
  {
    bf8_t kA[2][2], kB[2][2];
    loadK(0, kA); loadK(1, kB);
    auto qkexp = [&](bf8_t (&kk)[2][2]){
      f32x4 sacc[2][4];
      #pragma unroll
      for (int a=0;a<2;++a)
        #pragma unroll
        for (int b=0;b<4;++b) sacc[a][b] = f32x4{0.f,0.f,0.f,0.f};
      #pragma unroll
      for (int ks=0;ks<2;++ks)
        #pragma unroll
        for (int b=0;b<4;++b){
          sacc[0][b] = __builtin_amdgcn_mfma_f32_16x16x32_bf16(kk[0][ks], qf[b][ks], sacc[0][b], 0,0,0);
          sacc[1][b] = __builtin_amdgcn_mfma_f32_16x16x32_bf16(kk[1][ks], qf[b][ks], sacc[1][b], 0,0,0);
        }
      #pragma unroll
      for (int a=0;a<2;++a)
        #pragma unroll
        for (int b=0;b<4;++b)
          #pragma unroll
          for (int r=0;r<4;++r)
            rs[b] += __builtin_amdgcn_exp2f(sacc[a][b][r] * cexp);
    };
    for (int mt = 0; mt < 32; mt += 2){
      qkexp(kA);
      if (mt+2 < 32) loadK(mt+2, kA);
      qkexp(kB);
      if (mt+3 < 32) loadK(mt+3, kB);
    }
  }
  #pragma unroll
  for (int b=0;b<4;++b){ rs[b] += __shfl_xor(rs[b],16); rs[b] += __shfl_xor(rs[b],32); }
  {
    float* red = (float*)ls;                 // [4 waves][64 n] (aliases P0)
    if (lg == 0){
      #pragma unroll
      for (int b=0;b<4;++b) red[w*64 + b*16 + lr] = rs[b];
    }
    __syncthreads();
    float* rinv = (float*)(ls + 1024);
    if (t < 64) rinv[t] = 1.0f / (red[t] + red[64+t] + red[128+t] + red[192+t]);
    __syncthreads();
  }
  float lrv[4];
  #pragma unroll
  for (int b=0;b<4;++b) lrv[b] = log2f(((const float*)(ls + 1024))[b*16 + lr]);
  __syncthreads();                           // rinv fully consumed before P0 writes

  // ---- pass 2: p = exp2(s*cexp + log2(rinv)); P dbuf; colsums; PV ----
  f32x4 oacc[4];
  #pragma unroll
  for (int i=0;i<4;++i) oacc[i] = f32x4{0.f,0.f,0.f,0.f};
  {
    bf8_t kA[2][2], kB[2][2], vA[4], vB[4];
    loadK(0, kA); loadV(0, vA);
    loadK(1, kB); loadV(1, vB);
    auto step2 = [&](int mt, bf8_t (&kk)[2][2], bf8_t (&vv)[4], u32 pb){
      const int m0 = mt * 128;
      f32x4 sacc[2][4];
      #pragma unroll
      for (int a=0;a<2;++a)
        #pragma unroll
        for (int b=0;b<4;++b) sacc[a][b] = f32x4{0.f,0.f,0.f,0.f};
      #pragma unroll
      for (int ks=0;ks<2;++ks)
        #pragma unroll
        for (int b=0;b<4;++b){
          sacc[0][b] = __builtin_amdgcn_mfma_f32_16x16x32_bf16(kk[0][ks], qf[b][ks], sacc[0][b], 0,0,0);
          sacc[1][b] = __builtin_amdgcn_mfma_f32_16x16x32_bf16(kk[1][ks], qf[b][ks], sacc[1][b], 0,0,0);
        }
      if (mt+2 < 32) loadK(mt+2, kk);       // prefetch K (covered by ~2 iters)
      float cs[2][4];
      #pragma unroll
      for (int a=0;a<2;++a){ cs[a][0]=0.f; cs[a][1]=0.f; cs[a][2]=0.f; cs[a][3]=0.f; }
      #pragma unroll
      for (int a=0;a<2;++a){
        const u32 mbyte = (w*32 + a*16 + lg*4)*2;
        #pragma unroll
        for (int b=0;b<4;++b){
          const float p0 = __builtin_amdgcn_exp2f(sacc[a][b][0]*cexp + lrv[b]);
          const float p1 = __builtin_amdgcn_exp2f(sacc[a][b][1]*cexp + lrv[b]);
          const float p2 = __builtin_amdgcn_exp2f(sacc[a][b][2]*cexp + lrv[b]);
          const float p3 = __builtin_amdgcn_exp2f(sacc[a][b][3]*cexp + lrv[b]);
          cs[a][0]+=p0; cs[a][1]+=p1; cs[a][2]+=p2; cs[a][3]+=p3;
          u32 u01, u23;
          asm("v_cvt_pk_bf16_f32 %0, %1, %2" : "=v"(u01) : "v"(p0), "v"(p1));
          asm("v_cvt_pk_bf16_f32 %0, %1, %2" : "=v"(u23) : "v"(p2), "v"(p3));
          *(uint2*)(ls + pb + swzB(b*16 + lr, mbyte, 256)) = uint2{u01, u23};
        }
      }
      #pragma unroll
      for (int a=0;a<2;++a)
        #pragma unroll
        for (int r=0;r<4;++r){
          float v = cs[a][r];
          v += __shfl_xor(v,1); v += __shfl_xor(v,2);
          v += __shfl_xor(v,4); v += __shfl_xor(v,8);
          cs[a][r] = v;
        }
      if (lr == 0){
        const int base = (h*64 + nb)*4096 + m0 + w*32;
        #pragma unroll
        for (int a=0;a<2;++a)
          #pragma unroll
          for (int r=0;r<4;++r)
            Apart[base + a*16 + lg*4 + r] = cs[a][r];
      }
      __syncthreads();                       // P[pb] fully written (other buffer untouched)
      #pragma unroll
      for (int ks2 = 0; ks2 < 4; ++ks2) {
        const u32 co = ks2*64 + lg*16;
        #pragma unroll
        for (int i=0;i<4;++i){
          const bf8_t ap = *(const bf8_t*)(ls + pb + swzB(i*16 + lr, co, 256));
          oacc[i] = __builtin_amdgcn_mfma_f32_16x16x32_bf16(ap, vv[ks2], oacc[i], 0,0,0);
        }
      }
      if (mt+2 < 32) loadV(mt+2, vv);        // prefetch V after PV consumed it
    };
    for (int mt = 0; mt < 32; mt += 2){
      step2(mt,   kA, vA, 0);
      step2(mt+1, kB, vB, 16384);
    }
  }
  #pragma unroll
  for (int i=0;i<4;++i)
    #pragma unroll
    for (int r=0;r<4;++r){
      const int row = n0 + i*16 + lg*4 + r;
      const int col = qc0 + w*16 + lr;
      ov[row*512 + col] = f2bf(oacc[i][r]);
    }
}

// ---------------- A reduction: two-stage fp64 (deterministic fixed order), z/y = branch ----------
__global__ void k_reduceA1(const float* __restrict__ ApartB, double* __restrict__ A64p){
  const int br = blockIdx.z;
  const float* Apart = ApartB + (size_t)br*EL2M;
  const int m = blockIdx.x*256 + threadIdx.x;
  const int kb = blockIdx.y;                 // 8 chunks of 64 rows
  double s = 0.0;
  for (int b = kb*64; b < kb*64 + 64; ++b) s += (double)Apart[b*4096 + m];
  A64p[br*32768 + kb*4096 + m] = s;
}
__global__ void k_reduceA2(const double* __restrict__ A64p, double* __restrict__ A64){
  const int br = blockIdx.y;
  const int m = blockIdx.x*256 + threadIdx.x;
  double s = 0.0;
  #pragma unroll
  for (int kb=0;kb<8;++kb) s += A64p[br*32768 + kb*4096 + m];
  A64[br*4096 + m] = s;
}

// ---------------- exact stable-argsort top/bottom-K (wave-reduce version) ----------------
__global__ __launch_bounds__(256) void k_select(const double* __restrict__ A64B, int* __restrict__ idxB){
  __shared__ double Aw[4096];
  __shared__ double wv_[4];
  __shared__ int    wi_[4];
  const double* A64 = A64B + (size_t)blockIdx.x*4096;
  int* idx = idxB + blockIdx.x*32;
  const int t = threadIdx.x, w = t >> 6, lane = t & 63;
  for (int i=t;i<4096;i+=256) Aw[i] = A64[i];
  __syncthreads();
  for (int k=0;k<10;++k){                         // top-K: max, tie -> smaller index
    double best = -1e300; int bidx = 1<<30;
    for (int i=t;i<4096;i+=256){
      const double v = Aw[i];
      if (v > best){ best = v; bidx = i; }
    }
    #pragma unroll
    for (int m=1;m<64;m<<=1){
      const double ovv = __shfl_xor(best, m);
      const int    oii = __shfl_xor(bidx, m);
      if (ovv > best || (ovv == best && oii < bidx)){ best = ovv; bidx = oii; }
    }
    if (lane == 0){ wv_[w] = best; wi_[w] = bidx; }
    __syncthreads();
    if (t == 0){
      double bb = wv_[0]; int bi2 = wi_[0];
      #pragma unroll
      for (int q=1;q<4;++q)
        if (wv_[q] > bb || (wv_[q] == bb && wi_[q] < bi2)){ bb = wv_[q]; bi2 = wi_[q]; }
      idx[k] = bi2; Aw[bi2] = -1e300;
    }
    __syncthreads();
  }
  for (int i=t;i<4096;i+=256) Aw[i] = A64[i];
  __syncthreads();
  for (int k=0;k<10;++k){                         // bottom-K from the end: min, tie -> larger index
    double best = 1e300; int bidx = -1;
    for (int i=t;i<4096;i+=256){
      const double v = Aw[i];
      if (v < best || (v == best && i > bidx)){ best = v; bidx = i; }
    }
    #pragma unroll
    for (int m=1;m<64;m<<=1){
      const double ovv = __shfl_xor(best, m);
      const int    oii = __shfl_xor(bidx, m);
      if (ovv < best || (ovv == best && oii > bidx)){ best = ovv; bidx = oii; }
    }
    if (lane == 0){ wv_[w] = best; wi_[w] = bidx; }
    __syncthreads();
    if (t == 0){
      double bb = wv_[0]; int bi2 = wi_[0];
      #pragma unroll
      for (int q=1;q<4;++q)
        if (wv_[q] < bb || (wv_[q] == bb && wi_[q] > bi2)){ bb = wv_[q]; bi2 = wi_[q]; }
      idx[19-k] = bi2; Aw[bi2] = 1e300;
    }
    __syncthreads();
  }
}

// ---------------- residual GEMM (Wo): 1-term, residual epilogue, z=branch, async staging ----------
__global__ __launch_bounds__(256) void k_gemm_wo(
    const u16* __restrict__ ovB, const u16* __restrict__ wb,
    const float* __restrict__ xgB, float* __restrict__ AXB)
{
  __shared__ __align__(16) char ls[16384];   // A@0, B@8192
  const int br = blockIdx.z;
  const u16* Ahi  = ovB + (size_t)br*EL2M;
  const u16* Bthi = wb + (size_t)br*WBR + 4*262144;
  const float* resid = xgB + (size_t)br*EL2M;
  float* outF = AXB + (size_t)br*EL2M;
  const int t = threadIdx.x;
  const int w = t >> 6, lane = t & 63;
  const int n0 = blockIdx.x * 64;
  const int c0 = blockIdx.y * 64;
  const int wr = w >> 1, wc = w & 1;
  const int lr = lane & 15, lg = lane >> 4;

  auto stage = [&](const u16* __restrict__ src, char* lbase, int row0, int kb){
    #pragma unroll
    for (int j=0;j<2;++j){
      const int ci = w*128 + j*64 + lane;
      const int r  = ci >> 3, cl = ci & 7;
      const int cs = cl ^ (r & 7);
      gll16(src + (size_t)(row0 + r)*512 + kb + cs*8, lbase + w*2048 + j*1024);
    }
  };

  f32x4 acc[2][2];
  #pragma unroll
  for (int i=0;i<2;++i)
    #pragma unroll
    for (int j=0;j<2;++j) acc[i][j] = f32x4{0.f,0.f,0.f,0.f};

  for (int bk = 0; bk < 8; ++bk) {
    const int kb = bk * 64;
    __syncthreads();
    stage(Ahi,  ls,        n0, kb);
    stage(Bthi, ls + 8192, c0, kb);
    __syncthreads();
    #pragma unroll
    for (int ks = 0; ks < 2; ++ks) {
      const u32 co = ks*64 + lg*16;
      bf8_t ah[2], bh[2];
      #pragma unroll
      for (int i=0;i<2;++i) {
        ah[i] = *(const bf8_t*)(ls +        swzB(wr*32 + i*16 + lr, co, 128));
        bh[i] = *(const bf8_t*)(ls + 8192 + swzB(wc*32 + i*16 + lr, co, 128));
      }
      #pragma unroll
      for (int i=0;i<2;++i)
        #pragma unroll
        for (int j=0;j<2;++j)
          acc[i][j] = __builtin_amdgcn_mfma_f32_16x16x32_bf16(ah[i], bh[j], acc[i][j], 0,0,0);
    }
  }
  #pragma unroll
  for (int i=0;i<2;++i)
    #pragma unroll
    for (int j=0;j<2;++j) {
      const int col = c0 + wc*32 + j*16 + lr;
      #pragma unroll
      for (int r=0;r<4;++r) {
        const int row = n0 + wr*32 + i*16 + lg*4 + r;
        outF[row*512 + col] = acc[i][j][r] + resid[row*512 + col];
      }
    }
}

// ---------------- feats = LN(x_res): mean over rows (partials), and selected rows ----------------
__global__ __launch_bounds__(256) void k_slide_part(const float* __restrict__ AXB,
                                                    float* __restrict__ spartB){
  __shared__ float acc[4][512];
  const int br = blockIdx.y;
  const float* xres = AXB + (size_t)br*EL2M;
  float* spart = spartB + (size_t)br*32768;
  const int t = threadIdx.x, w = t >> 6, lane = t & 63;
  float la[8];
  #pragma unroll
  for (int i=0;i<8;++i) la[i]=0.f;
  for (int rr = 0; rr < 16; ++rr) {
    const int row = blockIdx.x*64 + w*16 + rr;
    const float* xr = xres + row*512;
    float v[8];
    f32x4 a  = *(const f32x4*)(xr + lane*8);
    f32x4 a2 = *(const f32x4*)(xr + lane*8 + 4);
    v[0]=a.x; v[1]=a.y; v[2]=a.z; v[3]=a.w; v[4]=a2.x; v[5]=a2.y; v[6]=a2.z; v[7]=a2.w;
    float s = v[0]+v[1]+v[2]+v[3]+v[4]+v[5]+v[6]+v[7];
    #pragma unroll
    for (int m=1;m<64;m<<=1) s += __shfl_xor(s, m);
    const float mean = s * (1.0f/512.0f);
    float q = 0.f;
    #pragma unroll
    for (int i=0;i<8;++i){ const float d = v[i]-mean; q += d*d; }
    #pragma unroll
    for (int m=1;m<64;m<<=1) q += __shfl_xor(q, m);
    const float rstd = 1.0f / sqrtf(q*(1.0f/512.0f) + 1e-5f);
    #pragma unroll
    for (int i=0;i<8;++i) la[i] += (v[i]-mean)*rstd;   // g,b applied at reduce (linear)
  }
  #pragma unroll
  for (int i=0;i<8;++i) acc[w][lane*8+i] = la[i];
  __syncthreads();
  for (int c = t; c < 512; c += 256)
    spart[blockIdx.x*512 + c] = acc[0][c]+acc[1][c]+acc[2][c]+acc[3][c];
}

__global__ void k_slide_reduce(const float* __restrict__ spartB, const float* __restrict__ g,
                               const float* __restrict__ b, float* __restrict__ tokB){
  const int br = blockIdx.y;
  const float* spart = spartB + (size_t)br*32768;
  const int c = blockIdx.x*256 + threadIdx.x;
  float s = 0.f;
  for (int bb=0;bb<64;++bb) s += spart[bb*512 + c];
  tokB[br*512 + c] = g[c]*(s*(1.0f/4096.0f)) + b[c];
}

__global__ void k_atte(const float* __restrict__ AXB, const int* __restrict__ idxB,
                       const float* __restrict__ g, const float* __restrict__ b,
                       float* __restrict__ atteB){
  const int br = blockIdx.y;
  const int i = blockIdx.x, lane = threadIdx.x;   // 64 threads = 1 wave
  const int row = idxB[br*32 + i];
  const float* xr = AXB + (size_t)br*EL2M + row*512;
  float v[8];
  f32x4 a  = *(const f32x4*)(xr + lane*8);
  f32x4 a2 = *(const f32x4*)(xr + lane*8 + 4);
  v[0]=a.x; v[1]=a.y; v[2]=a.z; v[3]=a.w; v[4]=a2.x; v[5]=a2.y; v[6]=a2.z; v[7]=a2.w;
  float s = v[0]+v[1]+v[2]+v[3]+v[4]+v[5]+v[6]+v[7];
  #pragma unroll
  for (int m=1;m<64;m<<=1) s += __shfl_xor(s, m);
  const float mean = s * (1.0f/512.0f);
  float q = 0.f;
  #pragma unroll
  for (int i2=0;i2<8;++i2){ const float d = v[i2]-mean; q += d*d; }
  #pragma unroll
  for (int m=1;m<64;m<<=1) q += __shfl_xor(q, m);
  const float rstd = 1.0f / sqrtf(q*(1.0f/512.0f) + 1e-5f);
  #pragma unroll
  for (int i2=0;i2<8;++i2){
    const int c = lane*8 + i2;
    atteB[br*10240 + i*512 + c] = (v[i2]-mean)*rstd*g[c] + b[c];
  }
}

// ---------------- head stage 1: concat GEMV split-K ----------------
__global__ __launch_bounds__(256) void k_fused_part(
    const float* __restrict__ tokB, const float* __restrict__ Wfc2,
    float* __restrict__ partF)
{
  __shared__ float part[8][32];
  const int t = threadIdx.x, jj = t & 31, rg = t >> 5;
  const int j = blockIdx.x*32 + jj;
  const int r0 = blockIdx.y*128;
  float s = 0.f;
  #pragma unroll 4
  for (int i = 0; i < 16; ++i){
    const int r = r0 + rg + i*8;
    s += tokB[r] * Wfc2[r*512 + j];   // tokB = [tokH(512) | tokI(512)] contiguous
  }
  part[rg][jj] = s;
  __syncthreads();
  if (t < 32){
    float acc = 0.f;
    #pragma unroll
    for (int g=0; g<8; ++g) acc += part[g][t];
    partF[blockIdx.y*512 + blockIdx.x*32 + t] = acc;
  }
}

// ---------------- head stage 2: g1 GEMV split-K; fused vector reconstructed inline --------------
__global__ __launch_bounds__(256) void k_g1_part(
    const float* __restrict__ tokB, const float* __restrict__ partF,
    const float* __restrict__ bfc2, const float* __restrict__ Wc1,
    float* __restrict__ partG)
{
  __shared__ float part[8][32];
  const int t = threadIdx.x, jj = t & 31, rg = t >> 5;
  const int j = blockIdx.x*32 + jj;
  const int r0 = blockIdx.y*128;
  float s = 0.f;
  #pragma unroll 4
  for (int i = 0; i < 16; ++i){
    const int r = r0 + rg + i*8;
    float xv;
    if (r < 512)      xv = tokB[r] + tokB[512 + r];
    else if (r < 1024) xv = tokB[r-512] * tokB[r];
    else {
      const int jr = r - 1024;
      xv = bfc2[jr];
      #pragma unroll
      for (int kb=0;kb<8;++kb) xv += partF[kb*512 + jr];
    }
    s += xv * Wc1[r*512 + j];
  }
  part[rg][jj] = s;
  __syncthreads();
  if (t < 32){
    float acc = 0.f;
    #pragma unroll
    for (int g=0; g<8; ++g) acc += part[g][t];
    partG[blockIdx.y*512 + blockIdx.x*32 + t] = acc;
  }
}

__global__ void k_g1_fin(const float* __restrict__ partG, const float* __restrict__ bc1,
                         float* __restrict__ g1)
{
  const int j = blockIdx.x*256 + threadIdx.x;   // 512
  float acc = bc1[j];
  #pragma unroll
  for (int kb=0;kb<12;++kb) acc += partG[kb*512 + j];
  g1[j] = 0.5f*acc*(1.0f + erff(acc*0.70710678118654752f));
}

// ---------------- head stage 3: Lm[20][20] cosine-sim matrix ----------------
__global__ __launch_bounds__(256) void k_lm(
    const float* __restrict__ atteB, const float* __restrict__ lscale, float* __restrict__ Lm)
{
  __shared__ float ra[512];
  __shared__ float nAs;
  const float* atteH = atteB;
  const float* atteI = atteB + 10240;
  const int a = blockIdx.x, t = threadIdx.x, w = t >> 6, l = t & 63;
  for (int i=t;i<512;i+=256) ra[i] = atteH[a*512+i];
  __syncthreads();
  if (w == 0){
    float s = 0.f;
    #pragma unroll
    for (int k=0;k<8;++k){ const float v = ra[l + k*64]; s += v*v; }
    #pragma unroll
    for (int m=1;m<64;m<<=1) s += __shfl_xor(s, m);
    if (l == 0) nAs = s;
  }
  __syncthreads();
  const float scale = expf(lscale[0]);
  const float nA = sqrtf(nAs);
  for (int bi = 0; bi < 5; ++bi){
    const int b = w + bi*4;
    float dot = 0.f, nb = 0.f;
    #pragma unroll
    for (int k=0;k<8;++k){
      const float vb = atteI[b*512 + l + k*64];
      dot += ra[l + k*64]*vb;
      nb  += vb*vb;
    }
    #pragma unroll
    for (int m=1;m<64;m<<=1){ dot += __shfl_xor(dot,m); nb += __shfl_xor(nb,m); }
    if (l == 0) Lm[a*20 + b] = scale * dot / (nA * sqrtf(nb));
  }
}

// ---------------- head stage 4: classifier logits + contrastive loss ----------------
__global__ __launch_bounds__(256) void k_loss(
    const float* __restrict__ tokB, const float* __restrict__ g1G, const float* __restrict__ LmG,
    const float* __restrict__ WheC, const float* __restrict__ bheC,
    const float* __restrict__ WihcC, const float* __restrict__ bihcC,
    const float* __restrict__ Wc2, const float* __restrict__ bc2,
    float* __restrict__ out)
{
  __shared__ float sH[512], sI[512], g1[512];
  __shared__ float Lm[20][20];
  __shared__ double terms[512];
  const int t = threadIdx.x, w = t >> 6, l = t & 63;
  for (int i=t;i<512;i+=256){ sH[i]=tokB[i]; sI[i]=tokB[512+i]; g1[i]=g1G[i]; }
  for (int i=t;i<400;i+=256) ((float*)Lm)[i] = LmG[i];
  __syncthreads();
  if (w < 3){
    const float* x  = (w==0)? sH   : (w==1)? sI    : g1;
    const float* W  = (w==0)? WheC : (w==1)? WihcC : Wc2;
    const float* bb = (w==0)? bheC : (w==1)? bihcC : bc2;
    const int c = l & 3, rg = l >> 2;
    float s = 0.f;
    for (int r = rg; r < 512; r += 16) s += x[r]*W[r*4+c];
    #pragma unroll
    for (int m=4;m<64;m<<=1) s += __shfl_xor(s, m);
    if (rg == 0) out[w*4 + c] = s + bb[c];
  }
  for (int e=t;e<512;e+=256){
    double res = 0.0;
    if (e < 400){
      const int r = e % 10, part = (e/10) % 2, i2 = (e/20) % 10, half = e/200;
      const int a = part ? (10 + r) : r;
      const int c0 = part ? (10 + i2) : i2;
      const int qb = part ? 0 : 10;
      auto Mget = [&](int aa, int bb)->double{
        return (double)(half ? Lm[bb][aa] : Lm[aa][bb]);
      };
      const double v0 = Mget(a, c0);
      double mx = v0;
      #pragma unroll
      for (int q=0;q<10;++q){ const double v = Mget(a, qb+q); if (v > mx) mx = v; }
      double se = exp(v0 - mx);
      #pragma unroll
      for (int q=0;q<10;++q) se += exp(Mget(a, qb+q) - mx);
      res = (log(se) + mx) - v0;
    }
    terms[e] = res;
  }
  __syncthreads();
  for (int s2=256;s2>0;s2>>=1){
    if (t < s2) terms[t] += terms[t+s2];
    __syncthreads();
  }
  if (t == 0) {
    const float cl = (float)(terms[0] / 400.0);
    out[12]=cl; out[13]=cl; out[14]=cl; out[15]=cl;
  }
}

// ---------------- launcher ----------------
extern "C" void kernel_launch(void* const* d_in, const int* in_sizes, int n_in,
                              void* d_out, int out_size, void* d_ws, size_t ws_size,
                              hipStream_t stream)
{
  (void)in_sizes; (void)n_in; (void)out_size; (void)ws_size;
  auto F = [&](int i){ return (const float*)d_in[i]; };
  char* ws = (char*)d_ws;
  size_t off = 0;
  auto alloc = [&](size_t sz)->void*{ void* p = ws + off; off += (sz + 255) & ~((size_t)255); return p; };

  float* xg   = (float*)alloc((size_t)2*EL2M*4);     // gelu(fc) output, 2 branches
  float* AX   = (float*)alloc((size_t)2*EL2M*4);     // Apart, later x_res, 2 branches
  u16*   shi  = (u16*)alloc((size_t)2*EL2M*2);       // LN(h) bf16
  u16*   qh   = (u16*)alloc((size_t)2*EL2M*2);
  u16*   kh   = (u16*)alloc((size_t)2*EL2M*2);
  u16*   vT   = (u16*)alloc((size_t)2*EL2M*2);       // V^T [d][n]
  u16*   ov   = (u16*)alloc((size_t)2*EL2M*2);       // attn out (pre-Wo)
  u16*   wb   = (u16*)alloc((size_t)2*WBR*2);        // weights: 5 slots x 2 branches
  double* A64p= (double*)alloc((size_t)2*32768*8);
  double* A64 = (double*)alloc((size_t)2*4096*8);
  int*   idxB = (int*)alloc(2*32*4);
  float* spart= (float*)alloc((size_t)2*32768*4);
  float* tokB = (float*)alloc(2*512*4);
  float* attB = (float*)alloc((size_t)2*10240*4);
  float* g1W    = (float*)alloc(512*4);
  float* LmW    = (float*)alloc(400*4);
  float* partF  = (float*)alloc((size_t)8*512*4);
  float* partG  = (float*)alloc((size_t)12*512*4);

  k_split_w<<<dim3(1024,5,2),256,0,stream>>>(
      F(2),F(8),F(9),F(10),F(11),      // HE:  Wfc Wq Wk Wv Wo
      F(4),F(14),F(15),F(16),F(17),    // IHC: Wfc Wq Wk Wv Wo
      wb);
  k_gemm_fc<<<dim3(64,8,2),256,0,stream>>>(F(0), F(1), wb, F(3), F(5), xg);
  k_ln<<<dim3(1024,2),256,0,stream>>>(xg, F(6), F(7), F(12), F(13), shi);
  k_gemm_qkv<<<dim3(64,8,2),256,0,stream>>>(shi, wb, qh, kh, vT);
  k_attn<<<1024,256,0,stream>>>(qh, kh, vT, ov, AX);
  k_reduceA1<<<dim3(16,8,2),256,0,stream>>>(AX, A64p);
  k_reduceA2<<<dim3(16,2),256,0,stream>>>(A64p, A64);
  k_select<<<2,256,0,stream>>>(A64, idxB);
  k_gemm_wo<<<dim3(64,8,2),256,0,stream>>>(ov, wb, xg, AX);
  k_slide_part<<<dim3(64,2),256,0,stream>>>(AX, spart);
  k_slide_reduce<<<dim3(2,2),256,0,stream>>>(spart, F(18), F(19), tokB);
  k_atte<<<dim3(20,2),64,0,stream>>>(AX, idxB, F(18), F(19), attB);

  k_fused_part<<<dim3(16,8),256,0,stream>>>(tokB, F(24), partF);
  k_g1_part<<<dim3(16,12),256,0,stream>>>(tokB, partF, F(25), F(26), partG);
  k_g1_fin<<<2,256,0,stream>>>(partG, F(27), g1W);
  k_lm<<<20,256,0,stream>>>(attB, F(30), LmW);
  k_loss<<<1,256,0,stream>>>(tokB, g1W, LmW,
                             F(20), F(21), F(22), F(23), F(28), F(29),
                             (float*)d_out);
}